// Round 25
// baseline (80.737 us; speedup 1.0000x reference)
//
#include <hip/hip_runtime.h>
#include <hip/hip_bf16.h>
#include <float.h>
#include <math.h>

#define NB 128
#define NQ 16
#define ND 800
#define NE 300
#define ZROW 50000                            // emb_table padding row (all zeros)

// workspace layout (float offsets). All regions written every call.
#define WS_SIM    0                          // [NB][NQ][ND] raw dots
#define WS_CTXINV (NB*NQ*ND)                 // [NB][ND] 1/(||ctx||/9+1e-9)
#define WS_SCORES (WS_CTXINV + NB*ND)        // [NB][NQ][13] (slots 6..12 used)
#define WS_C2     (WS_SCORES + NB*NQ*13)     // [NB][NQ][3][13 strips][2]
#define WS_QBF    (WS_C2 + NB*NQ*3*26)       // [NB][16][320] bf16

#define HP 164                                // staging pitch (floats); 164%32=4 -> 2-way banks

typedef __attribute__((ext_vector_type(8))) short short8;
typedef __attribute__((ext_vector_type(4))) float f32x4;
typedef __attribute__((ext_vector_type(4))) unsigned short ushort4v;

__device__ __forceinline__ unsigned short f2bf(float x) {   // RNE (header cast)
    union { __hip_bfloat16 h; unsigned short u; } cv;
    cv.h = __float2bfloat16(x);
    return cv.u;
}

__device__ __forceinline__ void ins6(float t[6], float v) {
    if (v > t[5]) t[5] = v;
    float a;
    if (t[5] > t[4]) { a = t[4]; t[4] = t[5]; t[5] = a; }
    if (t[4] > t[3]) { a = t[3]; t[3] = t[4]; t[4] = a; }
    if (t[3] > t[2]) { a = t[2]; t[2] = t[3]; t[3] = a; }
    if (t[2] > t[1]) { a = t[1]; t[1] = t[2]; t[2] = a; }
    if (t[1] > t[0]) { a = t[0]; t[0] = t[1]; t[1] = a; }
}

__device__ __forceinline__ void ins2(float& a1, float& a2, float v) {
    if (v > a2) a2 = v;
    if (a2 > a1) { float t = a1; a1 = a2; a2 = t; }
}

__device__ __forceinline__ void merge2(float& a1, float& a2, float b1v, float b2v) {
    float hi = fmaxf(a1, b1v), lo = fminf(a1, b1v);
    a1 = hi;
    a2 = fmaxf(lo, fmaxf(a2, b2v));
}

// ------- kq: q rows -> bf16 [16][320] (K-pad zeroed) + idf -------
__global__ __launch_bounds__(256) void kq(const int* __restrict__ qrls,
                                          const float* __restrict__ emb,
                                          const float* __restrict__ idf,
                                          float* __restrict__ ws) {
    int b = blockIdx.x;
    int tid = threadIdx.x;
    __shared__ int qrow[16];
    if (tid < 16) qrow[tid] = qrls[b * NQ + tid];
    __syncthreads();
    unsigned short* qbf = (unsigned short*)(ws + WS_QBF) + (size_t)b * 16 * 320;
    for (int it = tid; it < 1200; it += 256) {
        int q = it / 75, e4 = it - q * 75;
        float4 v = *(const float4*)(emb + (size_t)qrow[q] * NE + e4 * 4);
        ushort4v u;
        u[0] = f2bf(v.x); u[1] = f2bf(v.y); u[2] = f2bf(v.z); u[3] = f2bf(v.w);
        *(ushort4v*)(qbf + q * 320 + e4 * 4) = u;
    }
    if (tid < 160) {
        int q = tid / 10, p = tid - q * 10;
        *(unsigned*)(qbf + q * 320 + 300 + p * 2) = 0u;
    }
    if (tid < NQ)
        ws[WS_SCORES + (b * NQ + tid) * 13 + 12] = idf[qrow[tid]];
}

// ------- kfused: grid (3200), 256 thr = 4 waves, K-split staging -------
// XCD co-location with b as the SLOW index: bid%8 = XCD; kk = bid/8;
// strip = kk%25 (fast), b = xcd + 8*(kk/25) (slow). Consecutive blocks on an
// XCD walk the 25 strips of ONE b -> its ~1 MB doc-row set stays L2-hot.
// Per half h: stage 40 rows x 160 cols fp32 (pitch 164, glds, pads/OOB ->
// zero row). waves 0,1: MFMA sim; all waves: ctx rolling windows (8 each).
__global__ __launch_bounds__(256, 5) void kfused(const int* __restrict__ docw,
                                                 const float* __restrict__ emb,
                                                 float* __restrict__ ws) {
    int bid = blockIdx.x;
    int xcd = bid & 7;
    int kk = bid >> 3;                        // 0..399
    int strip = kk % 25;
    int b = xcd + 8 * (kk / 25);              // 0..127, b%8 == xcd, slow index
    int base = strip * 32;
    int tid = threadIdx.x;
    __shared__ float slds[6656];             // 26 glds-chunks x 1KB
    __shared__ int sidx[40];
    __shared__ float ACC[32][33];            // [window][paired-lane]

    int wv = tid >> 6, lane = tid & 63;

    if (tid < 40) {
        int rg = base - 4 + tid;
        sidx[tid] = (rg >= 0 && rg < ND) ? docw[b * ND + rg] : ZROW;
    }
    for (int i = tid; i < 32 * 33; i += 256) ((float*)ACC)[i] = 0.f;
    __syncthreads();

    int rsub = lane & 15, kgrp = lane >> 4;
    const unsigned short* qp = (const unsigned short*)(ws + WS_QBF)
                               + ((size_t)b * 16 + rsub) * 320 + kgrp * 8;
    int lrb = (4 + wv * 16 + rsub) * HP + kgrp * 8;   // used by wv<2
    int wb = wv * 8;                                  // ctx window base (8/wave)

    f32x4 acc = {0.f, 0.f, 0.f, 0.f};

#pragma unroll
    for (int h = 0; h < 2; ++h) {
        // ---- issue 26 x 1KB glds (linear dest; pads -> zero row) ----
        for (int j = wv; j < 26; j += 4) {
            int jj = __builtin_amdgcn_readfirstlane(j);
            int F = jj * 64 + lane;
            int r = F / 41;
            int c4 = F - r * 41;
            int g4 = h * 40 + c4;
            bool ok = (r < 40) && (c4 < 40) && (g4 < 75);
            int rowsrc = ok ? sidx[r] : ZROW;
            int colsrc = ok ? g4 * 4 : 0;
            const float* gp = emb + (size_t)rowsrc * NE + colsrc;
            __builtin_amdgcn_global_load_lds(
                (const __attribute__((address_space(1))) void*)gp,
                (__attribute__((address_space(3))) void*)&slds[(size_t)jj * 256],
                16, 0, 0);
        }
        __syncthreads();                     // drain; straight into compute

        if (wv < 2) {
            // ---- MFMA: K=160 exact (5 steps); pitch 164 -> 2-way banks ----
#pragma unroll
            for (int k = 0; k < 5; ++k) {
                int c0 = k * 32;
                float4 x0 = *(const float4*)&slds[lrb + c0];
                float4 x1 = *(const float4*)&slds[lrb + c0 + 4];
                short8 bf;
                bf[0] = (short)f2bf(x0.x); bf[1] = (short)f2bf(x0.y);
                bf[2] = (short)f2bf(x0.z); bf[3] = (short)f2bf(x0.w);
                bf[4] = (short)f2bf(x1.x); bf[5] = (short)f2bf(x1.y);
                bf[6] = (short)f2bf(x1.z); bf[7] = (short)f2bf(x1.w);
                short8 af = *(const short8*)(qp + h * 160 + c0);
                acc = __builtin_amdgcn_mfma_f32_16x16x32_bf16(af, bf, acc, 0, 0, 0);
            }
        }
        // ---- ctx-norm: ALL waves, 8 windows each (rows wb..wb+14) ----
        {
            float cw0 = 0.f, cw1 = 0.f, cw2 = 0.f;
            for (int i = 0; i < 15; ++i) {
                int r = wb + i;
                float2 va = *(const float2*)&slds[r * HP + 2 * lane];
                float vc = (lane < 32) ? slds[r * HP + 128 + lane] : 0.f;
                cw0 += va.x; cw1 += va.y; cw2 += vc;
                if (i >= 8) {
                    int r2 = r - 8;
                    float2 vb = *(const float2*)&slds[r2 * HP + 2 * lane];
                    float vd = (lane < 32) ? slds[r2 * HP + 128 + lane] : 0.f;
                    cw0 -= vb.x; cw1 -= vb.y; cw2 -= vd;
                }
                if (i >= 7) {
                    float s = fmaf(cw0, cw0, fmaf(cw1, cw1, cw2 * cw2));
                    s += __shfl_xor(s, 1);
                    if ((lane & 1) == 0)
                        ACC[r - 7][lane >> 1] += s;   // disjoint windows per wave
                }
            }
        }
        __syncthreads();                     // h0: protect LDS; h1: ACC gate
    }

    // ---- result writes ----
    if (wv < 2) {
        int col = base + wv * 16 + rsub;
        float* simp = ws + WS_SIM + (size_t)b * NQ * ND + col;
#pragma unroll
        for (int i = 0; i < 4; ++i)
            simp[(size_t)(kgrp * 4 + i) * ND] = acc[i];
    } else if (wv == 2 && lane < 32) {
        float s = 0.f;
#pragma unroll
        for (int j = 0; j < 32; ++j) s += ACC[lane][j];
        ws[WS_CTXINV + b * ND + base + lane] =
            1.f / (sqrtf(s) * (1.f / 9.f) + 1e-9f);
    }
}

// ------- ktail2: grid (2176), XCD co-located, b slow index:
// bid%8 = XCD; kk = bid/8; bx = kk%17 (fast), b = xcd + 8*(kk/17) (slow).
// bx<13: conv strip (64 cells, weights in LDS). bx>=13: scan group. -------
__global__ __launch_bounds__(256) void ktail2(const float* __restrict__ c1w,
                                              const float* __restrict__ c1b,
                                              const float* __restrict__ c2w,
                                              const float* __restrict__ c2b,
                                              const float* __restrict__ c3w,
                                              const float* __restrict__ c3b,
                                              float* __restrict__ ws) {
    int bid = blockIdx.x;
    int xcd = bid & 7;
    int kk = bid >> 3;                        // 0..271
    int bx = kk % 17;                         // 0..16 fast
    int b = xcd + 8 * (kk / 17);              // 0..127, b%8 == xcd, slow
    int tid = threadIdx.x;
    __shared__ float BUF[3216];              // conv: S[18][68]; scan: P[4][804]
    __shared__ float PART[4][16][6];
    __shared__ float WL[160 * 4];            // 32 filters x 5 float4
    int wv = tid >> 6, lane = tid & 63;

    if (bx < 13) {
        // ---- stage weights (once) + sim strip ----
        if (tid < 160) {
            int f = tid / 5, j = tid - f * 5;
            float4 w;
            if (j == 0)      w = make_float4(c3w[9*f],   c3w[9*f+1], c3w[9*f+2], c3w[9*f+3]);
            else if (j == 1) w = make_float4(c3w[9*f+4], c3w[9*f+5], c3w[9*f+6], c3w[9*f+7]);
            else if (j == 2) w = make_float4(c3w[9*f+8], c3b[f],     c1w[f],     c1b[f]);
            else if (j == 3) w = make_float4(c2w[4*f],   c2w[4*f+1], c2w[4*f+2], c2w[4*f+3]);
            else             w = make_float4(c2b[f],     0.f,        0.f,        0.f);
            *(float4*)&WL[tid * 4] = w;
        }
        int c0 = bx * 64;
        for (int idx = tid; idx < 18 * 66; idx += 256) {
            int r = idx / 66, c = idx % 66;
            int d = c0 + c;
            float v = 0.f;
            if (r < NQ && d < ND) v = ws[WS_SIM + (size_t)(b * NQ + r) * ND + d];
            BUF[r * 68 + c] = v;
        }
        __syncthreads();

        int q = tid & 15, dg = tid >> 4;     // dg 0..15
        int cb = dg * 4;
        float s0[6], s1[6], s2[6];
#pragma unroll
        for (int i = 0; i < 6; ++i) {
            s0[i] = BUF[q * 68 + cb + i];
            s1[i] = BUF[(q + 1) * 68 + cb + i];
            s2[i] = BUF[(q + 2) * 68 + cb + i];
        }
        float m1[4], m2[4], m3[4];
#pragma unroll
        for (int i = 0; i < 4; ++i) { m1[i] = -FLT_MAX; m2[i] = -FLT_MAX; m3[i] = -FLT_MAX; }
        const float4* WL4 = (const float4*)WL;
        for (int f = 0; f < 32; ++f) {       // LDS broadcast weight reads
            float4 wA = WL4[f * 5];          // c3w 0..3
            float4 wB = WL4[f * 5 + 1];      // c3w 4..7
            float4 wC = WL4[f * 5 + 2];      // {c3w8, c3b, c1w, c1b}
            float4 wD = WL4[f * 5 + 3];      // c2w 0..3
            float4 wE = WL4[f * 5 + 4];      // {c2b,..}
#pragma unroll
            for (int i = 0; i < 4; ++i) {
                float v1 = fmaf(wC.z, s0[i], wC.w);
                m1[i] = fmaxf(m1[i], v1);
                float v2 = wE.x;
                v2 = fmaf(wD.x, s0[i], v2); v2 = fmaf(wD.y, s0[i+1], v2);
                v2 = fmaf(wD.z, s1[i], v2); v2 = fmaf(wD.w, s1[i+1], v2);
                m2[i] = fmaxf(m2[i], v2);
                float v3 = wC.y;
                v3 = fmaf(wA.x, s0[i], v3); v3 = fmaf(wA.y, s0[i+1], v3); v3 = fmaf(wA.z, s0[i+2], v3);
                v3 = fmaf(wA.w, s1[i], v3); v3 = fmaf(wB.x, s1[i+1], v3); v3 = fmaf(wB.y, s1[i+2], v3);
                v3 = fmaf(wB.z, s2[i], v3); v3 = fmaf(wB.w, s2[i+1], v3); v3 = fmaf(wC.x, s2[i+2], v3);
                m3[i] = fmaxf(m3[i], v3);
            }
        }
        float a1[3] = {-FLT_MAX, -FLT_MAX, -FLT_MAX};
        float a2[3] = {-FLT_MAX, -FLT_MAX, -FLT_MAX};
#pragma unroll
        for (int i = 0; i < 4; ++i) {
            if (c0 + cb + i < ND) {
                ins2(a1[0], a2[0], fmaxf(m1[i], 0.f));
                ins2(a1[1], a2[1], fmaxf(m2[i], 0.f));
                ins2(a1[2], a2[2], fmaxf(m3[i], 0.f));
            }
        }
#pragma unroll
        for (int m = 16; m <= 32; m <<= 1) {  // merge the wave's 4 dg per q
#pragma unroll
            for (int ng = 0; ng < 3; ++ng) {
                float b1v = __shfl_xor(a1[ng], m), b2v = __shfl_xor(a2[ng], m);
                merge2(a1[ng], a2[ng], b1v, b2v);
            }
        }
        if (lane < 16) {
#pragma unroll
            for (int ng = 0; ng < 3; ++ng) {
                PART[wv][lane][ng * 2]     = a1[ng];
                PART[wv][lane][ng * 2 + 1] = a2[ng];
            }
        }
        __syncthreads();
        if (tid < 16) {
            float* c2p = ws + WS_C2 + ((size_t)(b * NQ + tid) * 3) * 26 + bx * 2;
#pragma unroll
            for (int ng = 0; ng < 3; ++ng) {
                float x1 = PART[0][tid][ng * 2], x2 = PART[0][tid][ng * 2 + 1];
#pragma unroll
                for (int p = 1; p < 4; ++p)
                    merge2(x1, x2, PART[p][tid][ng * 2], PART[p][tid][ng * 2 + 1]);
                c2p[ng * 26] = x1; c2p[ng * 26 + 1] = x2;
            }
        }
    } else {
        // ---- scan group: prefix scan + ctx cosine + top6, 4 q rows ----
        int q = (bx - 13) * 4 + wv;
        float* P = &BUF[wv * 804];
        const float* simrow = ws + WS_SIM + (size_t)(b * NQ + q) * ND;
        const float* cinv = ws + WS_CTXINV + (size_t)b * ND;
        float carry = 0.f;
        for (int c = 0; c < 13; ++c) {
            int d = c * 64 + lane;
            float v = (d < ND) ? simrow[d] : 0.f;
#pragma unroll
            for (int off = 1; off < 64; off <<= 1) {
                float t = __shfl_up(v, off);
                if (lane >= off) v += t;
            }
            v += carry;
            if (d < ND) P[d] = v;
            carry = __shfl(v, 63);
        }
        float top[6] = {-FLT_MAX,-FLT_MAX,-FLT_MAX,-FLT_MAX,-FLT_MAX,-FLT_MAX};
        for (int c = 0; c < 13; ++c) {
            int d = c * 64 + lane;
            if (d < ND) {
                int hi_i = (d + 3 < ND) ? d + 3 : ND - 1;
                float hi = P[hi_i];
                float lo = (d >= 5) ? P[d - 5] : 0.f;
                float ctx = (hi - lo) * (1.f / 9.f) * cinv[d];
                ins6(top, ctx);
            }
        }
#pragma unroll
        for (int m = 1; m < 64; m <<= 1) {
            float o0 = __shfl_xor(top[0], m), o1 = __shfl_xor(top[1], m);
            float o2 = __shfl_xor(top[2], m), o3 = __shfl_xor(top[3], m);
            float o4 = __shfl_xor(top[4], m), o5 = __shfl_xor(top[5], m);
            ins6(top, o0); ins6(top, o1); ins6(top, o2);
            ins6(top, o3); ins6(top, o4); ins6(top, o5);
        }
        if (lane == 0) {
            float* sc = ws + WS_SCORES + (size_t)(b * NQ + q) * 13;
            sc[6] = top[0]; sc[7] = top[1]; sc[8]  = top[2];
            sc[9] = top[3]; sc[10] = top[4]; sc[11] = top[5];
        }
    }
}

// ------- kmlp: 13-strip merge + scores gather + 208->32->32->1 -------
__global__ __launch_bounds__(64) void kmlp(const float* __restrict__ w1,
                                           const float* __restrict__ b1,
                                           const float* __restrict__ w2,
                                           const float* __restrict__ b2,
                                           const float* __restrict__ w3,
                                           const float* __restrict__ b3,
                                           const float* __restrict__ ws,
                                           float* __restrict__ out) {
    int b = blockIdx.x, tid = threadIdx.x;
    __shared__ float sc[208];
    const float* s = ws + WS_SCORES + (size_t)b * 208;
    for (int i = tid; i < 208; i += 64)
        if ((i % 13) >= 6) sc[i] = s[i];            // slots 6..12
    if (tid < 48) {                                  // slots 0..5 from C2
        int q = tid / 3, ng = tid % 3;
        const float* p = ws + WS_C2 + ((size_t)(b * NQ + q) * 3 + ng) * 26;
        float x1 = p[0], x2 = p[1];
#pragma unroll
        for (int st = 1; st < 13; ++st) merge2(x1, x2, p[st * 2], p[st * 2 + 1]);
        sc[q * 13 + ng * 2] = x1; sc[q * 13 + ng * 2 + 1] = x2;
    }
    __syncthreads();
    int j = tid & 31, half = tid >> 5;
    float a = 0.f;
    int i0 = half * 104;
    for (int i = 0; i < 104; ++i) a = fmaf(sc[i0 + i], w1[(i0 + i) * 32 + j], a);
    a += __shfl_xor(a, 32);
    a = fmaxf(a + b1[j], 0.f);                       // both halves hold h_j
    float a2v = 0.f;
    for (int k = 0; k < 32; ++k) {
        float hk = __shfl(a, k);
        a2v = fmaf(hk, w2[k * 32 + j], a2v);
    }
    a2v = fmaxf(a2v + b2[j], 0.f);
    float r = a2v * w3[j];
    if (half) r = 0.f;
#pragma unroll
    for (int m = 1; m <= 32; m <<= 1) r += __shfl_xor(r, m);
    if (tid == 0) out[b] = r + b3[0];
}

extern "C" void kernel_launch(void* const* d_in, const int* in_sizes, int n_in,
                              void* d_out, int out_size, void* d_ws, size_t ws_size,
                              hipStream_t stream) {
    (void)in_sizes; (void)n_in; (void)out_size; (void)ws_size;
    const int*   qrls = (const int*)d_in[0];
    const int*   docw = (const int*)d_in[1];
    const float* emb  = (const float*)d_in[2];
    const float* idf  = (const float*)d_in[3];
    const float* c1w  = (const float*)d_in[4];
    const float* c1b  = (const float*)d_in[5];
    const float* c2w  = (const float*)d_in[6];
    const float* c2b  = (const float*)d_in[7];
    const float* c3w  = (const float*)d_in[8];
    const float* c3b  = (const float*)d_in[9];
    const float* w1   = (const float*)d_in[10];
    const float* b1   = (const float*)d_in[11];
    const float* w2   = (const float*)d_in[12];
    const float* b2   = (const float*)d_in[13];
    const float* w3   = (const float*)d_in[14];
    const float* b3   = (const float*)d_in[15];
    float* ws  = (float*)d_ws;
    float* out = (float*)d_out;

    kq<<<dim3(NB), 256, 0, stream>>>(qrls, emb, idf, ws);
    kfused<<<dim3(3200), 256, 0, stream>>>(docw, emb, ws);
    ktail2<<<dim3(2176), 256, 0, stream>>>(c1w, c1b, c2w, c2b, c3w, c3b, ws);
    kmlp<<<dim3(NB), 64, 0, stream>>>(w1, b1, w2, b2, w3, b3, ws, out);
}

// Round 26
// 76.492 us; speedup vs baseline: 1.0555x; 1.0555x over previous
//
#include <hip/hip_runtime.h>
#include <hip/hip_bf16.h>
#include <float.h>
#include <math.h>

#define NB 128
#define NQ 16
#define ND 800
#define NE 300
#define ZROW 50000                            // emb_table padding row (all zeros)

// workspace layout (float offsets). All regions written every call.
#define WS_SIM    0                          // [NB][NQ][ND] raw dots
#define WS_CTXINV (NB*NQ*ND)                 // [NB][ND] 1/(||ctx||/9+1e-9)
#define WS_SCORES (WS_CTXINV + NB*ND)        // [NB][NQ][13] (slots 6..12 used)
#define WS_C2     (WS_SCORES + NB*NQ*13)     // [NB][NQ][3][13 strips][2]
#define WS_QBF    (WS_C2 + NB*NQ*3*26)       // [NB][16][320] bf16

#define HP 164                                // staging pitch (floats); 164%32=4 -> 2-way banks

typedef __attribute__((ext_vector_type(8))) short short8;
typedef __attribute__((ext_vector_type(4))) float f32x4;
typedef __attribute__((ext_vector_type(4))) unsigned short ushort4v;

__device__ __forceinline__ unsigned short f2bf(float x) {   // RNE (header cast)
    union { __hip_bfloat16 h; unsigned short u; } cv;
    cv.h = __float2bfloat16(x);
    return cv.u;
}

__device__ __forceinline__ void ins6(float t[6], float v) {
    if (v > t[5]) t[5] = v;
    float a;
    if (t[5] > t[4]) { a = t[4]; t[4] = t[5]; t[5] = a; }
    if (t[4] > t[3]) { a = t[3]; t[3] = t[4]; t[4] = a; }
    if (t[3] > t[2]) { a = t[2]; t[2] = t[3]; t[3] = a; }
    if (t[2] > t[1]) { a = t[1]; t[1] = t[2]; t[2] = a; }
    if (t[1] > t[0]) { a = t[0]; t[0] = t[1]; t[1] = a; }
}

__device__ __forceinline__ void ins2(float& a1, float& a2, float v) {
    if (v > a2) a2 = v;
    if (a2 > a1) { float t = a1; a1 = a2; a2 = t; }
}

__device__ __forceinline__ void merge2(float& a1, float& a2, float b1v, float b2v) {
    float hi = fmaxf(a1, b1v), lo = fminf(a1, b1v);
    a1 = hi;
    a2 = fmaxf(lo, fmaxf(a2, b2v));
}

// ------- kq: q rows -> bf16 [16][320] (K-pad zeroed) + idf -------
__global__ __launch_bounds__(256) void kq(const int* __restrict__ qrls,
                                          const float* __restrict__ emb,
                                          const float* __restrict__ idf,
                                          float* __restrict__ ws) {
    int b = blockIdx.x;
    int tid = threadIdx.x;
    __shared__ int qrow[16];
    if (tid < 16) qrow[tid] = qrls[b * NQ + tid];
    __syncthreads();
    unsigned short* qbf = (unsigned short*)(ws + WS_QBF) + (size_t)b * 16 * 320;
    for (int it = tid; it < 1200; it += 256) {
        int q = it / 75, e4 = it - q * 75;
        float4 v = *(const float4*)(emb + (size_t)qrow[q] * NE + e4 * 4);
        ushort4v u;
        u[0] = f2bf(v.x); u[1] = f2bf(v.y); u[2] = f2bf(v.z); u[3] = f2bf(v.w);
        *(ushort4v*)(qbf + q * 320 + e4 * 4) = u;
    }
    if (tid < 160) {
        int q = tid / 10, p = tid - q * 10;
        *(unsigned*)(qbf + q * 320 + 300 + p * 2) = 0u;
    }
    if (tid < NQ)
        ws[WS_SCORES + (b * NQ + tid) * 13 + 12] = idf[qrow[tid]];
}

// ------- kfused: grid (3200), 256 thr = 4 waves, K-split staging -------
// XCD co-location (r24-proven decode): bid%8 = XCD; kk = bid/8;
// b = xcd + 8*(kk&15) (fast), strip = kk>>4 (slow). All 25 strip-blocks of
// batch item b land on the same XCD -> shared doc-row set is L2/L3-local.
// Per half h: stage 40 rows x 160 cols fp32 (pitch 164, glds, pads/OOB ->
// zero row). waves 0,1: MFMA sim; all waves: ctx rolling windows (8 each).
__global__ __launch_bounds__(256, 5) void kfused(const int* __restrict__ docw,
                                                 const float* __restrict__ emb,
                                                 float* __restrict__ ws) {
    int bid = blockIdx.x;
    int xcd = bid & 7;
    int kk = bid >> 3;                        // 0..399
    int b = xcd + 8 * (kk & 15);              // 0..127, b%8 == xcd
    int base = (kk >> 4) * 32;                // strip 0..24
    int tid = threadIdx.x;
    __shared__ float slds[6656];             // 26 glds-chunks x 1KB
    __shared__ int sidx[40];
    __shared__ float ACC[32][33];            // [window][paired-lane]

    int wv = tid >> 6, lane = tid & 63;

    if (tid < 40) {
        int rg = base - 4 + tid;
        sidx[tid] = (rg >= 0 && rg < ND) ? docw[b * ND + rg] : ZROW;
    }
    for (int i = tid; i < 32 * 33; i += 256) ((float*)ACC)[i] = 0.f;
    __syncthreads();

    int rsub = lane & 15, kgrp = lane >> 4;
    const unsigned short* qp = (const unsigned short*)(ws + WS_QBF)
                               + ((size_t)b * 16 + rsub) * 320 + kgrp * 8;
    int lrb = (4 + wv * 16 + rsub) * HP + kgrp * 8;   // used by wv<2
    int wb = wv * 8;                                  // ctx window base (8/wave)

    f32x4 acc = {0.f, 0.f, 0.f, 0.f};

#pragma unroll
    for (int h = 0; h < 2; ++h) {
        // ---- issue 26 x 1KB glds (linear dest; pads -> zero row) ----
        for (int j = wv; j < 26; j += 4) {
            int jj = __builtin_amdgcn_readfirstlane(j);
            int F = jj * 64 + lane;
            int r = F / 41;
            int c4 = F - r * 41;
            int g4 = h * 40 + c4;
            bool ok = (r < 40) && (c4 < 40) && (g4 < 75);
            int rowsrc = ok ? sidx[r] : ZROW;
            int colsrc = ok ? g4 * 4 : 0;
            const float* gp = emb + (size_t)rowsrc * NE + colsrc;
            __builtin_amdgcn_global_load_lds(
                (const __attribute__((address_space(1))) void*)gp,
                (__attribute__((address_space(3))) void*)&slds[(size_t)jj * 256],
                16, 0, 0);
        }
        __syncthreads();                     // drain; straight into compute

        if (wv < 2) {
            // ---- MFMA: K=160 exact (5 steps); pitch 164 -> 2-way banks ----
#pragma unroll
            for (int k = 0; k < 5; ++k) {
                int c0 = k * 32;
                float4 x0 = *(const float4*)&slds[lrb + c0];
                float4 x1 = *(const float4*)&slds[lrb + c0 + 4];
                short8 bf;
                bf[0] = (short)f2bf(x0.x); bf[1] = (short)f2bf(x0.y);
                bf[2] = (short)f2bf(x0.z); bf[3] = (short)f2bf(x0.w);
                bf[4] = (short)f2bf(x1.x); bf[5] = (short)f2bf(x1.y);
                bf[6] = (short)f2bf(x1.z); bf[7] = (short)f2bf(x1.w);
                short8 af = *(const short8*)(qp + h * 160 + c0);
                acc = __builtin_amdgcn_mfma_f32_16x16x32_bf16(af, bf, acc, 0, 0, 0);
            }
        }
        // ---- ctx-norm: ALL waves, 8 windows each (rows wb..wb+14) ----
        {
            float cw0 = 0.f, cw1 = 0.f, cw2 = 0.f;
            for (int i = 0; i < 15; ++i) {
                int r = wb + i;
                float2 va = *(const float2*)&slds[r * HP + 2 * lane];
                float vc = (lane < 32) ? slds[r * HP + 128 + lane] : 0.f;
                cw0 += va.x; cw1 += va.y; cw2 += vc;
                if (i >= 8) {
                    int r2 = r - 8;
                    float2 vb = *(const float2*)&slds[r2 * HP + 2 * lane];
                    float vd = (lane < 32) ? slds[r2 * HP + 128 + lane] : 0.f;
                    cw0 -= vb.x; cw1 -= vb.y; cw2 -= vd;
                }
                if (i >= 7) {
                    float s = fmaf(cw0, cw0, fmaf(cw1, cw1, cw2 * cw2));
                    s += __shfl_xor(s, 1);
                    if ((lane & 1) == 0)
                        ACC[r - 7][lane >> 1] += s;   // disjoint windows per wave
                }
            }
        }
        __syncthreads();                     // h0: protect LDS; h1: ACC gate
    }

    // ---- result writes ----
    if (wv < 2) {
        int col = base + wv * 16 + rsub;
        float* simp = ws + WS_SIM + (size_t)b * NQ * ND + col;
#pragma unroll
        for (int i = 0; i < 4; ++i)
            simp[(size_t)(kgrp * 4 + i) * ND] = acc[i];
    } else if (wv == 2 && lane < 32) {
        float s = 0.f;
#pragma unroll
        for (int j = 0; j < 32; ++j) s += ACC[lane][j];
        ws[WS_CTXINV + b * ND + base + lane] =
            1.f / (sqrtf(s) * (1.f / 9.f) + 1e-9f);
    }
}

// ------- ktail2: grid (2176), XCD co-located (r24 decode): bid%8 = XCD,
// b = xcd + 8*(kk&15), bx = kk>>4 (0..16). bx<13: conv strip (64 cells,
// weights in LDS). bx>=13: scan group (4 q rows). -------
__global__ __launch_bounds__(256) void ktail2(const float* __restrict__ c1w,
                                              const float* __restrict__ c1b,
                                              const float* __restrict__ c2w,
                                              const float* __restrict__ c2b,
                                              const float* __restrict__ c3w,
                                              const float* __restrict__ c3b,
                                              float* __restrict__ ws) {
    int bid = blockIdx.x;
    int xcd = bid & 7;
    int kk = bid >> 3;                        // 0..271
    int b = xcd + 8 * (kk & 15);              // 0..127, b%8 == xcd
    int bx = kk >> 4;                         // 0..16
    int tid = threadIdx.x;
    __shared__ float BUF[3216];              // conv: S[18][68]; scan: P[4][804]
    __shared__ float PART[4][16][6];
    __shared__ float WL[160 * 4];            // 32 filters x 5 float4
    int wv = tid >> 6, lane = tid & 63;

    if (bx < 13) {
        // ---- stage weights (once) + sim strip ----
        if (tid < 160) {
            int f = tid / 5, j = tid - f * 5;
            float4 w;
            if (j == 0)      w = make_float4(c3w[9*f],   c3w[9*f+1], c3w[9*f+2], c3w[9*f+3]);
            else if (j == 1) w = make_float4(c3w[9*f+4], c3w[9*f+5], c3w[9*f+6], c3w[9*f+7]);
            else if (j == 2) w = make_float4(c3w[9*f+8], c3b[f],     c1w[f],     c1b[f]);
            else if (j == 3) w = make_float4(c2w[4*f],   c2w[4*f+1], c2w[4*f+2], c2w[4*f+3]);
            else             w = make_float4(c2b[f],     0.f,        0.f,        0.f);
            *(float4*)&WL[tid * 4] = w;
        }
        int c0 = bx * 64;
        for (int idx = tid; idx < 18 * 66; idx += 256) {
            int r = idx / 66, c = idx % 66;
            int d = c0 + c;
            float v = 0.f;
            if (r < NQ && d < ND) v = ws[WS_SIM + (size_t)(b * NQ + r) * ND + d];
            BUF[r * 68 + c] = v;
        }
        __syncthreads();

        int q = tid & 15, dg = tid >> 4;     // dg 0..15
        int cb = dg * 4;
        float s0[6], s1[6], s2[6];
#pragma unroll
        for (int i = 0; i < 6; ++i) {
            s0[i] = BUF[q * 68 + cb + i];
            s1[i] = BUF[(q + 1) * 68 + cb + i];
            s2[i] = BUF[(q + 2) * 68 + cb + i];
        }
        float m1[4], m2[4], m3[4];
#pragma unroll
        for (int i = 0; i < 4; ++i) { m1[i] = -FLT_MAX; m2[i] = -FLT_MAX; m3[i] = -FLT_MAX; }
        const float4* WL4 = (const float4*)WL;
        for (int f = 0; f < 32; ++f) {       // LDS broadcast weight reads
            float4 wA = WL4[f * 5];          // c3w 0..3
            float4 wB = WL4[f * 5 + 1];      // c3w 4..7
            float4 wC = WL4[f * 5 + 2];      // {c3w8, c3b, c1w, c1b}
            float4 wD = WL4[f * 5 + 3];      // c2w 0..3
            float4 wE = WL4[f * 5 + 4];      // {c2b,..}
#pragma unroll
            for (int i = 0; i < 4; ++i) {
                float v1 = fmaf(wC.z, s0[i], wC.w);
                m1[i] = fmaxf(m1[i], v1);
                float v2 = wE.x;
                v2 = fmaf(wD.x, s0[i], v2); v2 = fmaf(wD.y, s0[i+1], v2);
                v2 = fmaf(wD.z, s1[i], v2); v2 = fmaf(wD.w, s1[i+1], v2);
                m2[i] = fmaxf(m2[i], v2);
                float v3 = wC.y;
                v3 = fmaf(wA.x, s0[i], v3); v3 = fmaf(wA.y, s0[i+1], v3); v3 = fmaf(wA.z, s0[i+2], v3);
                v3 = fmaf(wA.w, s1[i], v3); v3 = fmaf(wB.x, s1[i+1], v3); v3 = fmaf(wB.y, s1[i+2], v3);
                v3 = fmaf(wB.z, s2[i], v3); v3 = fmaf(wB.w, s2[i+1], v3); v3 = fmaf(wC.x, s2[i+2], v3);
                m3[i] = fmaxf(m3[i], v3);
            }
        }
        float a1[3] = {-FLT_MAX, -FLT_MAX, -FLT_MAX};
        float a2[3] = {-FLT_MAX, -FLT_MAX, -FLT_MAX};
#pragma unroll
        for (int i = 0; i < 4; ++i) {
            if (c0 + cb + i < ND) {
                ins2(a1[0], a2[0], fmaxf(m1[i], 0.f));
                ins2(a1[1], a2[1], fmaxf(m2[i], 0.f));
                ins2(a1[2], a2[2], fmaxf(m3[i], 0.f));
            }
        }
#pragma unroll
        for (int m = 16; m <= 32; m <<= 1) {  // merge the wave's 4 dg per q
#pragma unroll
            for (int ng = 0; ng < 3; ++ng) {
                float b1v = __shfl_xor(a1[ng], m), b2v = __shfl_xor(a2[ng], m);
                merge2(a1[ng], a2[ng], b1v, b2v);
            }
        }
        if (lane < 16) {
#pragma unroll
            for (int ng = 0; ng < 3; ++ng) {
                PART[wv][lane][ng * 2]     = a1[ng];
                PART[wv][lane][ng * 2 + 1] = a2[ng];
            }
        }
        __syncthreads();
        if (tid < 16) {
            float* c2p = ws + WS_C2 + ((size_t)(b * NQ + tid) * 3) * 26 + bx * 2;
#pragma unroll
            for (int ng = 0; ng < 3; ++ng) {
                float x1 = PART[0][tid][ng * 2], x2 = PART[0][tid][ng * 2 + 1];
#pragma unroll
                for (int p = 1; p < 4; ++p)
                    merge2(x1, x2, PART[p][tid][ng * 2], PART[p][tid][ng * 2 + 1]);
                c2p[ng * 26] = x1; c2p[ng * 26 + 1] = x2;
            }
        }
    } else {
        // ---- scan group: prefix scan + ctx cosine + top6, 4 q rows ----
        int q = (bx - 13) * 4 + wv;
        float* P = &BUF[wv * 804];
        const float* simrow = ws + WS_SIM + (size_t)(b * NQ + q) * ND;
        const float* cinv = ws + WS_CTXINV + (size_t)b * ND;
        float carry = 0.f;
        for (int c = 0; c < 13; ++c) {
            int d = c * 64 + lane;
            float v = (d < ND) ? simrow[d] : 0.f;
#pragma unroll
            for (int off = 1; off < 64; off <<= 1) {
                float t = __shfl_up(v, off);
                if (lane >= off) v += t;
            }
            v += carry;
            if (d < ND) P[d] = v;
            carry = __shfl(v, 63);
        }
        float top[6] = {-FLT_MAX,-FLT_MAX,-FLT_MAX,-FLT_MAX,-FLT_MAX,-FLT_MAX};
        for (int c = 0; c < 13; ++c) {
            int d = c * 64 + lane;
            if (d < ND) {
                int hi_i = (d + 3 < ND) ? d + 3 : ND - 1;
                float hi = P[hi_i];
                float lo = (d >= 5) ? P[d - 5] : 0.f;
                float ctx = (hi - lo) * (1.f / 9.f) * cinv[d];
                ins6(top, ctx);
            }
        }
#pragma unroll
        for (int m = 1; m < 64; m <<= 1) {
            float o0 = __shfl_xor(top[0], m), o1 = __shfl_xor(top[1], m);
            float o2 = __shfl_xor(top[2], m), o3 = __shfl_xor(top[3], m);
            float o4 = __shfl_xor(top[4], m), o5 = __shfl_xor(top[5], m);
            ins6(top, o0); ins6(top, o1); ins6(top, o2);
            ins6(top, o3); ins6(top, o4); ins6(top, o5);
        }
        if (lane == 0) {
            float* sc = ws + WS_SCORES + (size_t)(b * NQ + q) * 13;
            sc[6] = top[0]; sc[7] = top[1]; sc[8]  = top[2];
            sc[9] = top[3]; sc[10] = top[4]; sc[11] = top[5];
        }
    }
}

// ------- kmlp: 13-strip merge + scores gather + 208->32->32->1 -------
__global__ __launch_bounds__(64) void kmlp(const float* __restrict__ w1,
                                           const float* __restrict__ b1,
                                           const float* __restrict__ w2,
                                           const float* __restrict__ b2,
                                           const float* __restrict__ w3,
                                           const float* __restrict__ b3,
                                           const float* __restrict__ ws,
                                           float* __restrict__ out) {
    int b = blockIdx.x, tid = threadIdx.x;
    __shared__ float sc[208];
    const float* s = ws + WS_SCORES + (size_t)b * 208;
    for (int i = tid; i < 208; i += 64)
        if ((i % 13) >= 6) sc[i] = s[i];            // slots 6..12
    if (tid < 48) {                                  // slots 0..5 from C2
        int q = tid / 3, ng = tid % 3;
        const float* p = ws + WS_C2 + ((size_t)(b * NQ + q) * 3 + ng) * 26;
        float x1 = p[0], x2 = p[1];
#pragma unroll
        for (int st = 1; st < 13; ++st) merge2(x1, x2, p[st * 2], p[st * 2 + 1]);
        sc[q * 13 + ng * 2] = x1; sc[q * 13 + ng * 2 + 1] = x2;
    }
    __syncthreads();
    int j = tid & 31, half = tid >> 5;
    float a = 0.f;
    int i0 = half * 104;
    for (int i = 0; i < 104; ++i) a = fmaf(sc[i0 + i], w1[(i0 + i) * 32 + j], a);
    a += __shfl_xor(a, 32);
    a = fmaxf(a + b1[j], 0.f);                       // both halves hold h_j
    float a2v = 0.f;
    for (int k = 0; k < 32; ++k) {
        float hk = __shfl(a, k);
        a2v = fmaf(hk, w2[k * 32 + j], a2v);
    }
    a2v = fmaxf(a2v + b2[j], 0.f);
    float r = a2v * w3[j];
    if (half) r = 0.f;
#pragma unroll
    for (int m = 1; m <= 32; m <<= 1) r += __shfl_xor(r, m);
    if (tid == 0) out[b] = r + b3[0];
}

extern "C" void kernel_launch(void* const* d_in, const int* in_sizes, int n_in,
                              void* d_out, int out_size, void* d_ws, size_t ws_size,
                              hipStream_t stream) {
    (void)in_sizes; (void)n_in; (void)out_size; (void)ws_size;
    const int*   qrls = (const int*)d_in[0];
    const int*   docw = (const int*)d_in[1];
    const float* emb  = (const float*)d_in[2];
    const float* idf  = (const float*)d_in[3];
    const float* c1w  = (const float*)d_in[4];
    const float* c1b  = (const float*)d_in[5];
    const float* c2w  = (const float*)d_in[6];
    const float* c2b  = (const float*)d_in[7];
    const float* c3w  = (const float*)d_in[8];
    const float* c3b  = (const float*)d_in[9];
    const float* w1   = (const float*)d_in[10];
    const float* b1   = (const float*)d_in[11];
    const float* w2   = (const float*)d_in[12];
    const float* b2   = (const float*)d_in[13];
    const float* w3   = (const float*)d_in[14];
    const float* b3   = (const float*)d_in[15];
    float* ws  = (float*)d_ws;
    float* out = (float*)d_out;

    kq<<<dim3(NB), 256, 0, stream>>>(qrls, emb, idf, ws);
    kfused<<<dim3(3200), 256, 0, stream>>>(docw, emb, ws);
    ktail2<<<dim3(2176), 256, 0, stream>>>(c1w, c1b, c2w, c2b, c3w, c3b, ws);
    kmlp<<<dim3(NB), 64, 0, stream>>>(w1, b1, w2, b2, w3, b3, ws, out);
}